// Round 17
// baseline (116.629 us; speedup 1.0000x reference)
//
#include <hip/hip_runtime.h>
#include <hip/hip_bf16.h>
#include <stdint.h>

#define HEADS 16
#define DH    64
#define SEQ   1024
#define DIM   1024

typedef __attribute__((ext_vector_type(8))) short bf16x8;
typedef __attribute__((ext_vector_type(4))) float f32x4;
typedef __attribute__((ext_vector_type(16))) float f32x16;
typedef __attribute__((ext_vector_type(4))) unsigned int u32x4;

// 0.125 * log2(e): folded into Q at GEMM epilogue so softmax uses exp2 directly
#define QSCALE_L2 0.18033688011112042f
// 8 nats in log2 units (defer-max threshold, T13)
#define THR_L2 11.541560327111707f
#define PEN_L2 (-14427.0f)   // -10000 * log2(e)

static __device__ __forceinline__ unsigned short f2bf(float f) {
  unsigned u = __builtin_bit_cast(unsigned, f);
  u += 0x7fff + ((u >> 16) & 1);   // RNE
  return (unsigned short)(u >> 16);
}

static __device__ __forceinline__ float fexp2(float x) {
#if __has_builtin(__builtin_amdgcn_exp2f)
  return __builtin_amdgcn_exp2f(x);
#else
  return exp2f(x);
#endif
}

static __device__ __forceinline__ void gload_lds16(const void* g, void* l) {
  __builtin_amdgcn_global_load_lds(
      (const __attribute__((address_space(1))) unsigned int*)g,
      (__attribute__((address_space(3))) unsigned int*)l,
      16, 0, 0);
}

// ---------------- Kernel P: fused prep (cvt_x | transpose_w | build_keep) ----
// blockIdx.x: [0,8192) cvt_x ; [8192,8960) transpose_w ; [8960,8968) build_keep
// build_keep emits the KEEP-LIST kl[b][iv] = n (iv-th kept position) + nkeep.
__global__ __launch_bounds__(256) void prep(
    const float* __restrict__ x, unsigned short* __restrict__ xb,
    const float* __restrict__ w, unsigned short* __restrict__ wT,
    const int* __restrict__ mask, int* __restrict__ kl,
    int* __restrict__ nkeep) {
  __shared__ unsigned short t[64][68];
  __shared__ int sc[256];
  const int bidx = blockIdx.x;
  const int tid = threadIdx.x;

  if (bidx < 8192) {
    const int i = (bidx * 256 + tid) * 4;
    const float4 v = *reinterpret_cast<const float4*>(x + i);
    short4 o;
    o.x = (short)f2bf(v.x);
    o.y = (short)f2bf(v.y);
    o.z = (short)f2bf(v.z);
    o.w = (short)f2bf(v.w);
    *reinterpret_cast<short4*>(xb + i) = o;
  } else if (bidx < 8960) {
    const int lin = bidx - 8192;
    const int bk = lin & 15;
    const int bn = lin >> 4;
    const int r = tid >> 4;
    const int c = (tid & 15) * 4;
#pragma unroll
    for (int rr = 0; rr < 64; rr += 16) {
      const float4 v = *reinterpret_cast<const float4*>(
          w + (size_t)(bk * 64 + r + rr) * 3072 + bn * 64 + c);
      t[r + rr][c + 0] = f2bf(v.x);
      t[r + rr][c + 1] = f2bf(v.y);
      t[r + rr][c + 2] = f2bf(v.z);
      t[r + rr][c + 3] = f2bf(v.w);
    }
    __syncthreads();
#pragma unroll
    for (int rr = 0; rr < 64; rr += 16) {
      short4 o;
      o.x = (short)t[c + 0][r + rr];
      o.y = (short)t[c + 1][r + rr];
      o.z = (short)t[c + 2][r + rr];
      o.w = (short)t[c + 3][r + rr];
      *reinterpret_cast<short4*>(
          wT + (size_t)(bn * 64 + r + rr) * 1024 + bk * 64 + c) = o;
    }
  } else {
    const int b = bidx - 8960;
    int kept[4];
    int c = 0;
#pragma unroll
    for (int k = 0; k < 4; ++k) {
      const int j = tid * 4 + k;
      const int kp = (j == 0) ? 1 : (mask[b * (SEQ - 1) + j - 1] != 0);
      kept[k] = kp;
      c += kp;
    }
    sc[tid] = c;
    __syncthreads();
    for (int off = 1; off < 256; off <<= 1) {
      const int v = (tid >= off) ? sc[tid - off] : 0;
      __syncthreads();
      sc[tid] += v;
      __syncthreads();
    }
    int pos = sc[tid] - c;
    const int total = sc[255];
#pragma unroll
    for (int k = 0; k < 4; ++k) {
      const int j = tid * 4 + k;
      if (kept[k]) kl[b * SEQ + pos] = j;
      pos += kept[k];
    }
    if (tid == 0) nkeep[b] = total;
  }
}

// ---------------- Kernel 1: qkv GEMM, Q-full + KV-compacted -----------------
// SINGLE-BARRIER 2-PHASE PIPELINE (guide T3-minimum recipe, m230-validated):
//   STAGE(buf^1, t+1) -> ds_read(buf)+MFMA(t) -> __syncthreads -> swap.
// The compiler's mandatory vmcnt(0)+lgkmcnt(0) drain before s_barrier now
// lands AFTER the MFMA phase, so prefetch loads hide under compute. One
// barrier per K-tile (round 9's failed variant had two + an early drain).
// 128x128 tile, BK=64, 2x32KB double-buffered LDS, XOR8 swizzle both sides.
// blocks [0,512):   Q  = x[all rows] @ wT[0:1024]      -> Qh (pre-scaled)
//   m FAST (bq&63): each m-tile pinned to one XCD across n-passes.
// blocks [512,1536): KV = x[kept rows via kl] @ wT[1024:]
//   K -> Kc[bh][i][64]; V -> Vt[bh][64 d][1024 i] transposed in-epilogue.
//   Pad/tail rows hold finite garbage; annihilated by the attention tail
//   pen (exp2(s-14427)==0 in f32) — bit-exact.
__global__ __launch_bounds__(256, 2) void qkv_gemm(
    const unsigned short* __restrict__ x, const unsigned short* __restrict__ wT,
    const int* __restrict__ kl, const int* __restrict__ nkeep,
    unsigned short* __restrict__ Qh, unsigned short* __restrict__ Kc,
    unsigned short* __restrict__ Vt) {
  __shared__ alignas(16) unsigned char La[2][128 * 128];  // 2x16KB A dbuf
  __shared__ alignas(16) unsigned char Lb[2][128 * 128];  // 2x16KB B dbuf
  const int tid = threadIdx.x;
  const int lane = tid & 63;
  const int wave = tid >> 6;
  const int bq = blockIdx.x;

  int m0, n0, nkb;
  int srow[4];                       // global A-row per staged row slot
  const int rbase = tid >> 3;        // staged row offset within 32-row group
  if (bq < 512) {
    m0 = (bq & 63) * 128;            // m FAST: 64 M-tiles over 8192 rows
    n0 = (bq >> 6) * 128;            // 8 N-tiles over Q section (slow)
    nkb = 1 << 30;
#pragma unroll
    for (int r = 0; r < 4; ++r) srow[r] = m0 + r * 32 + rbase;
  } else {
    const int idx = bq - 512;
    const int nt = idx >> 6;         // 16 N-tiles (slow)
    const int bm = idx & 63;         // (b,mt) FAST
    const int b = bm >> 3;
    const int mt = bm & 7;           // 8 compact M-tiles of 128
    nkb = nkeep[b];
    const int m0c = mt * 128;
    if (m0c >= nkb) return;          // whole block exits before any barrier
    m0 = b * 1024 + m0c;             // epilogue: grow>>10 = b, grow&1023 = iv
    n0 = 1024 + nt * 128;
#pragma unroll
    for (int r = 0; r < 4; ++r) {
      int i = m0c + r * 32 + rbase;
      i = (i < nkb) ? i : (nkb - 1); // clamp pad rows to last kept row
      srow[r] = b * 1024 + kl[b * SEQ + i];
    }
  }

  const int wm = (wave >> 1) * 64;
  const int wn = (wave & 1) * 64;
  const int l15 = lane & 15;
  const int lg = lane >> 4;
  const int lg4 = lg * 4;
  const int scha = (tid & 7) ^ ((tid >> 3) & 7);   // thread-fixed src swizzle

  f32x4 acc[4][4] = {};

  auto STAGE = [&](int buf, int kt) {
#pragma unroll
    for (int r = 0; r < 4; ++r) {
      const int o = r * 4096 + tid * 16;
      gload_lds16(x + (size_t)srow[r] * DIM + kt + scha * 8, &La[buf][o]);
      gload_lds16(wT + (size_t)(n0 + r * 32 + rbase) * DIM + kt + scha * 8,
                  &Lb[buf][o]);
    }
  };

  STAGE(0, 0);
  __syncthreads();          // prologue drain: tile 0 resident

  int cur = 0;
  for (int t = 0; t < 16; ++t) {
    if (t + 1 < 16) STAGE(cur ^ 1, (t + 1) * 64);   // issue prefetch FIRST
#pragma unroll
    for (int kk = 0; kk < 2; ++kk) {
      bf16x8 af[4], bfr[4];
#pragma unroll
      for (int i = 0; i < 4; ++i) {
        const int ra = wm + i * 16 + l15;
        af[i] = *reinterpret_cast<const bf16x8*>(
            &La[cur][ra * 128 + (((kk * 4 + lg) ^ (ra & 7)) << 4)]);
        const int rb = wn + i * 16 + l15;
        bfr[i] = *reinterpret_cast<const bf16x8*>(
            &Lb[cur][rb * 128 + (((kk * 4 + lg) ^ (rb & 7)) << 4)]);
      }
#pragma unroll
      for (int i = 0; i < 4; ++i)
#pragma unroll
        for (int j = 0; j < 4; ++j)
          acc[i][j] = __builtin_amdgcn_mfma_f32_16x16x32_bf16(
              af[i], bfr[j], acc[i][j], 0, 0, 0);
    }
    __syncthreads();   // compiler drains vmcnt(0)+lgkmcnt(0) HERE, after MFMA
    cur ^= 1;
  }

  // ---- epilogue: LDS bounce -> 16B coalesced stores ----
  const int sec = n0 >> 10;              // block-uniform: 0=q 1=k 2=v
  const int h = ((n0 + wn) >> 6) & 15;   // wave-uniform head
  const int bb = m0 >> 10;
  if (sec < 2) {
    // row-major path (Q, K): Sw[16 rows][72]
    unsigned short* Sw = reinterpret_cast<unsigned short*>(&La[0][0] + wave * 2304);
    const float sc = (sec == 0) ? QSCALE_L2 : 1.0f;
#pragma unroll
    for (int i = 0; i < 4; ++i) {
#pragma unroll
      for (int j = 0; j < 4; ++j)
#pragma unroll
        for (int r = 0; r < 4; ++r)
          Sw[(lg4 + r) * 72 + j * 16 + l15] = f2bf(acc[i][j][r] * sc);
#pragma unroll
      for (int pass = 0; pass < 2; ++pass) {
        const int row = pass * 8 + (lane >> 3);
        const int chunk = lane & 7;
        const bf16x8 vv = *reinterpret_cast<const bf16x8*>(&Sw[row * 72 + chunk * 8]);
        const int grow = m0 + wm + i * 16 + row;
        const int b = grow >> 10;
        const int n = grow & 1023;
        const size_t bh = (size_t)b * HEADS + h;
        if (sec == 0) {
          *reinterpret_cast<bf16x8*>(&Qh[(bh * SEQ + n) * DH + chunk * 8]) = vv;
        } else if (n < nkb) {            // n IS the compact index here
          *reinterpret_cast<bf16x8*>(&Kc[(bh * SEQ + n) * DH + chunk * 8]) = vv;
        }
      }
    }
  } else {
    // V path: d-major bounce Sv[64 d][24-short stride] -> direct transposed
    // store Vt[bh][d][iv]. Lane owns d=lane, stores two contiguous 16B chunks.
    unsigned short* Sv = reinterpret_cast<unsigned short*>(&La[0][0] + wave * 3072);
    const size_t bh = (size_t)bb * HEADS + h;
    unsigned short* vbase = Vt + (bh * DH + lane) * SEQ;
#pragma unroll
    for (int i = 0; i < 4; ++i) {
#pragma unroll
      for (int j = 0; j < 4; ++j)
#pragma unroll
        for (int r = 0; r < 4; ++r)
          Sv[(j * 16 + l15) * 24 + lg4 + r] = f2bf(acc[i][j][r]);
      const int iv0 = (m0 & 1023) + wm + i * 16;   // compact-i base, mult of 16
      const bf16x8 v0 = *reinterpret_cast<const bf16x8*>(&Sv[lane * 24 + 0]);
      const bf16x8 v1 = *reinterpret_cast<const bf16x8*>(&Sv[lane * 24 + 8]);
      *reinterpret_cast<bf16x8*>(vbase + iv0 + 0) = v0;
      *reinterpret_cast<bf16x8*>(vbase + iv0 + 8) = v1;
    }
  }
}

// ---------------- Kernel 2: flash attention over compacted KV ---------------
// block = 4 waves x 32 q-rows of one (b,h); 32x32x16 MFMA.
// K and V staged in double-buffered LDS via global_load_lds (one copy/block).
// XOR chunk-swizzle on the GLOBAL source + ds_read address (rule #21).
// Mask pen is tail-tile-only and computed in registers (kv < nk).
__global__ __launch_bounds__(256) void attn_fwd5(
    const unsigned short* __restrict__ Qh, const unsigned short* __restrict__ Kc,
    const unsigned short* __restrict__ Vtc,
    const int* __restrict__ nkeep, float* __restrict__ out) {
  __shared__ alignas(16) unsigned char Kl[2][8192];
  __shared__ alignas(16) unsigned char Vl[2][8192];
  __shared__ float corrw[4][32];
  const int tid = threadIdx.x;
  const int lane = tid & 63;
  const int wave = tid >> 6;
  const int l31 = lane & 31;
  const int hi = lane >> 5;
  const int h8 = hi * 8;
  const bool islo = lane < 32;

  // XCD swizzle: 128 consecutive logical blocks (16 heads) per XCD
  const int bid = ((blockIdx.x & 7) << 7) | (blockIdx.x >> 3);
  const int b = bid >> 7;
  const int hh = (bid >> 3) & 15;
  const int qc = bid & 7;
  const size_t bh = (size_t)b * HEADS + hh;
  const int q0 = qc * 128 + wave * 32;

  const int nk = nkeep[b];
  const int ntile = (nk + 63) >> 6;

  const unsigned short* Q = Qh + bh * SEQ * DH;
  const unsigned short* K = Kc + bh * SEQ * DH;
  const unsigned short* V = Vtc + bh * DH * SEQ;   // [64][1024] compacted cols

  auto STAGE = [&](int buf, int kt) {
#pragma unroll
    for (int p = 0; p < 2; ++p) {
      const int off = p * 4096 + tid * 16;
      const int row = off >> 7;
      const int chunk = (off >> 4) & 7;
      const int sch = chunk ^ (row & 7);
      gload_lds16(K + (size_t)(kt + row) * DH + sch * 8, &Kl[buf][off]);
      gload_lds16(V + (size_t)row * SEQ + kt + sch * 8, &Vl[buf][off]);
    }
  };

  STAGE(0, 0);

  bf16x8 qf[4];
#pragma unroll
  for (int ds = 0; ds < 4; ++ds)
    qf[ds] = *reinterpret_cast<const bf16x8*>(
        Q + (size_t)(q0 + l31) * DH + ds * 16 + h8);

  u32x4 onesu = {0u, 0u, 0u, 0u};
  onesu.x = islo ? 0x3F80u : 0u;     // bf16 1.0 at k==0 of lane-half 0
  const bf16x8 onesf = __builtin_bit_cast(bf16x8, onesu);

  f32x16 Od0 = (f32x16)0.f, Od1 = (f32x16)0.f;
  float m_ = 0.f, l_ = 0.f;

  __syncthreads();   // drains prologue STAGE

  int cur = 0;
  for (int ti = 0; ti < ntile; ++ti) {
    const int kt = ti * 64;
    if (ti + 1 < ntile) STAGE(cur ^ 1, kt + 64);

    // ---- S^T = K·Q^T from LDS (swizzled ds_read_b128) ----
    f32x16 st0 = (f32x16)0.f, st1 = (f32x16)0.f;
    __builtin_amdgcn_s_setprio(1);
#pragma unroll
    for (int ds = 0; ds < 4; ++ds) {
      const int c0 = (ds * 2 + hi) ^ (l31 & 7);
      const bf16x8 kf0 = *reinterpret_cast<const bf16x8*>(
          &Kl[cur][l31 * 128 + c0 * 16]);
      st0 = __builtin_amdgcn_mfma_f32_32x32x16_bf16(kf0, qf[ds], st0, 0, 0, 0);
      const bf16x8 kf1 = *reinterpret_cast<const bf16x8*>(
          &Kl[cur][(32 + l31) * 128 + c0 * 16]);
      st1 = __builtin_amdgcn_mfma_f32_32x32x16_bf16(kf1, qf[ds], st1, 0, 0, 0);
    }
    __builtin_amdgcn_s_setprio(0);

    // tail-only mask via rank-1 MFMA: st[kv][q] += pen[kv], pen = (kv<nk)?0:-1e4*log2e
    if (ti == ntile - 1) {
      const unsigned short pv = f2bf(PEN_L2);
      const unsigned short pu0 = (kt + l31 < nk) ? (unsigned short)0 : pv;
      const unsigned short pu1 = (kt + 32 + l31 < nk) ? (unsigned short)0 : pv;
      u32x4 p0 = {0u, 0u, 0u, 0u}, p1 = {0u, 0u, 0u, 0u};
      p0.x = islo ? (unsigned)pu0 : 0u;
      p1.x = islo ? (unsigned)pu1 : 0u;
      st0 = __builtin_amdgcn_mfma_f32_32x32x16_bf16(
          __builtin_bit_cast(bf16x8, p0), onesf, st0, 0, 0, 0);
      st1 = __builtin_amdgcn_mfma_f32_32x32x16_bf16(
          __builtin_bit_cast(bf16x8, p1), onesf, st1, 0, 0, 0);
    }
    // row max
    float a[8];
#pragma unroll
    for (int i = 0; i < 8; ++i)
      a[i] = fmaxf(fmaxf(st0[i], st0[i + 8]), fmaxf(st1[i], st1[i + 8]));
#pragma unroll
    for (int k = 4; k >= 1; k >>= 1)
#pragma unroll
      for (int i = 0; i < k; ++i) a[i] = fmaxf(a[i], a[i + k]);
    const float mx = fmaxf(a[0], __shfl_xor(a[0], 32));
    // deferred rescale (rare)
    if (!__all(mx <= m_ + THR_L2)) {
      const float mn = fmaxf(m_, mx);
      const float corr = fexp2(m_ - mn);
      m_ = mn;
      l_ *= corr;
      if (islo) corrw[wave][l31] = corr;
      f32x4 cv[4];
#pragma unroll
      for (int j = 0; j < 4; ++j)
        cv[j] = *reinterpret_cast<const f32x4*>(&corrw[wave][j * 8 + (h8 >> 1)]);
#pragma unroll
      for (int r = 0; r < 16; ++r) {
        Od0[r] *= cv[r >> 2][r & 3];
        Od1[r] *= cv[r >> 2][r & 3];
      }
    }
    // P = exp2(st - m)
#pragma unroll
    for (int i = 0; i < 16; ++i) {
      st0[i] = fexp2(st0[i] - m_);
      st1[i] = fexp2(st1[i] - m_);
    }
    // row sum
    float s8[8];
#pragma unroll
    for (int i = 0; i < 8; ++i)
      s8[i] = (st0[i] + st0[i + 8]) + (st1[i] + st1[i + 8]);
#pragma unroll
    for (int k = 4; k >= 1; k >>= 1)
#pragma unroll
      for (int i = 0; i < k; ++i) s8[i] += s8[i + k];
    l_ += s8[0] + __shfl_xor(s8[0], 32);
    // pack P -> A-frags (cvt_pk + permlane32_swap)
    bf16x8 pf[4];
#pragma unroll
    for (int t = 0; t < 2; ++t) {
#pragma unroll
      for (int bq = 0; bq < 2; ++bq) {
        const int o = 8 * bq;
        float e0 = t ? st1[o + 0] : st0[o + 0], e1 = t ? st1[o + 1] : st0[o + 1];
        float e2 = t ? st1[o + 2] : st0[o + 2], e3 = t ? st1[o + 3] : st0[o + 3];
        float e4 = t ? st1[o + 4] : st0[o + 4], e5 = t ? st1[o + 5] : st0[o + 5];
        float e6 = t ? st1[o + 6] : st0[o + 6], e7 = t ? st1[o + 7] : st0[o + 7];
        unsigned A0, A1, B0, B1;
        asm("v_cvt_pk_bf16_f32 %0, %1, %2" : "=v"(A0) : "v"(e0), "v"(e1));
        asm("v_cvt_pk_bf16_f32 %0, %1, %2" : "=v"(A1) : "v"(e2), "v"(e3));
        asm("v_cvt_pk_bf16_f32 %0, %1, %2" : "=v"(B0) : "v"(e4), "v"(e5));
        asm("v_cvt_pk_bf16_f32 %0, %1, %2" : "=v"(B1) : "v"(e6), "v"(e7));
        asm("v_permlane32_swap_b32 %0, %1\n\ts_nop 1" : "+v"(A0), "+v"(B0));
        asm("v_permlane32_swap_b32 %0, %1\n\ts_nop 1" : "+v"(A1), "+v"(B1));
        u32x4 pk4;
        pk4.x = A0; pk4.y = A1; pk4.z = B0; pk4.w = B1;
        pf[t * 2 + bq] = __builtin_bit_cast(bf16x8, pk4);
      }
    }
    // ---- PV from LDS V tile (swizzled ds_read_b128) ----
    __builtin_amdgcn_s_setprio(1);
#pragma unroll
    for (int kvs = 0; kvs < 4; ++kvs) {
      const int c0 = (kvs * 2 + hi) ^ (l31 & 7);
      const bf16x8 v0 = *reinterpret_cast<const bf16x8*>(
          &Vl[cur][l31 * 128 + c0 * 16]);
      Od0 = __builtin_amdgcn_mfma_f32_32x32x16_bf16(pf[kvs], v0, Od0, 0, 0, 0);
      const bf16x8 v1 = *reinterpret_cast<const bf16x8*>(
          &Vl[cur][(32 + l31) * 128 + c0 * 16]);
      Od1 = __builtin_amdgcn_mfma_f32_32x32x16_bf16(pf[kvs], v1, Od1, 0, 0, 0);
    }
    __builtin_amdgcn_s_setprio(0);

    __syncthreads();
    cur ^= 1;
  }

  // epilogue: O / l
  if (islo) corrw[wave][l31] = 1.0f / l_;
  f32x4 lv[4];
#pragma unroll
  for (int j = 0; j < 4; ++j)
    lv[j] = *reinterpret_cast<const f32x4*>(&corrw[wave][j * 8 + (h8 >> 1)]);
#pragma unroll
  for (int r = 0; r < 16; ++r) {
    const int q = q0 + (r & 3) + 8 * (r >> 2) + (hi << 2);
    out[((size_t)b * SEQ + q) * (HEADS * DH) + hh * DH + 0 * 32 + l31] =
        Od0[r] * lv[r >> 2][r & 3];
    out[((size_t)b * SEQ + q) * (HEADS * DH) + hh * DH + 1 * 32 + l31] =
        Od1[r] * lv[r >> 2][r & 3];
  }
}

// ---------------- launch ----------------------------------------------------
extern "C" void kernel_launch(void* const* d_in, const int* in_sizes, int n_in,
                              void* d_out, int out_size, void* d_ws, size_t ws_size,
                              hipStream_t stream) {
  const float* x = (const float*)d_in[0];
  const int* mask = (const int*)d_in[1];
  const float* w = (const float*)d_in[2];
  float* outp = (float*)d_out;

  char* ws = (char*)d_ws;
  unsigned short* xb   = (unsigned short*)(ws);                  // 16777216 B
  unsigned short* wT   = (unsigned short*)(ws + 16777216);       //  6291456 B
  unsigned short* Qh   = (unsigned short*)(ws + 23068672);       // 16777216 B
  unsigned short* Kc   = (unsigned short*)(ws + 39845888);       // 16777216 B
  unsigned short* Vt   = (unsigned short*)(ws + 56623104);       // 16777216 B
  int*            kl   = (int*)(ws + 73400320);                  //    32768 B
  int*            nkp  = (int*)(ws + 73433088);                  //       32 B

  prep<<<dim3(8968), 256, 0, stream>>>(x, xb, w, wT, mask, kl, nkp);
  qkv_gemm<<<dim3(1536), 256, 0, stream>>>(xb, wT, kl, nkp, Qh, Kc, Vt);
  attn_fwd5<<<dim3(1024), 256, 0, stream>>>(Qh, Kc, Vt, nkp, outp);
}

// Round 18
// 113.594 us; speedup vs baseline: 1.0267x; 1.0267x over previous
//
#include <hip/hip_runtime.h>
#include <hip/hip_bf16.h>
#include <stdint.h>

#define HEADS 16
#define DH    64
#define SEQ   1024
#define DIM   1024

typedef __attribute__((ext_vector_type(8))) short bf16x8;
typedef __attribute__((ext_vector_type(4))) float f32x4;
typedef __attribute__((ext_vector_type(16))) float f32x16;
typedef __attribute__((ext_vector_type(4))) unsigned int u32x4;

// 0.125 * log2(e): folded into Q at GEMM epilogue so softmax uses exp2 directly
#define QSCALE_L2 0.18033688011112042f
// 8 nats in log2 units (defer-max threshold, T13)
#define THR_L2 11.541560327111707f
#define PEN_L2 (-14427.0f)   // -10000 * log2(e)

static __device__ __forceinline__ unsigned short f2bf(float f) {
  unsigned u = __builtin_bit_cast(unsigned, f);
  u += 0x7fff + ((u >> 16) & 1);   // RNE
  return (unsigned short)(u >> 16);
}

static __device__ __forceinline__ float fexp2(float x) {
#if __has_builtin(__builtin_amdgcn_exp2f)
  return __builtin_amdgcn_exp2f(x);
#else
  return exp2f(x);
#endif
}

static __device__ __forceinline__ void gload_lds16(const void* g, void* l) {
  __builtin_amdgcn_global_load_lds(
      (const __attribute__((address_space(1))) unsigned int*)g,
      (__attribute__((address_space(3))) unsigned int*)l,
      16, 0, 0);
}

// ---------------- Kernel P: fused prep (cvt_x | transpose_w | build_keep) ----
// blockIdx.x: [0,8192) cvt_x ; [8192,8960) transpose_w ; [8960,8968) build_keep
// build_keep emits the KEEP-LIST kl[b][iv] = n (iv-th kept position) + nkeep.
__global__ __launch_bounds__(256) void prep(
    const float* __restrict__ x, unsigned short* __restrict__ xb,
    const float* __restrict__ w, unsigned short* __restrict__ wT,
    const int* __restrict__ mask, int* __restrict__ kl,
    int* __restrict__ nkeep) {
  __shared__ unsigned short t[64][68];
  __shared__ int sc[256];
  const int bidx = blockIdx.x;
  const int tid = threadIdx.x;

  if (bidx < 8192) {
    const int i = (bidx * 256 + tid) * 4;
    const float4 v = *reinterpret_cast<const float4*>(x + i);
    short4 o;
    o.x = (short)f2bf(v.x);
    o.y = (short)f2bf(v.y);
    o.z = (short)f2bf(v.z);
    o.w = (short)f2bf(v.w);
    *reinterpret_cast<short4*>(xb + i) = o;
  } else if (bidx < 8960) {
    const int lin = bidx - 8192;
    const int bk = lin & 15;
    const int bn = lin >> 4;
    const int r = tid >> 4;
    const int c = (tid & 15) * 4;
#pragma unroll
    for (int rr = 0; rr < 64; rr += 16) {
      const float4 v = *reinterpret_cast<const float4*>(
          w + (size_t)(bk * 64 + r + rr) * 3072 + bn * 64 + c);
      t[r + rr][c + 0] = f2bf(v.x);
      t[r + rr][c + 1] = f2bf(v.y);
      t[r + rr][c + 2] = f2bf(v.z);
      t[r + rr][c + 3] = f2bf(v.w);
    }
    __syncthreads();
#pragma unroll
    for (int rr = 0; rr < 64; rr += 16) {
      short4 o;
      o.x = (short)t[c + 0][r + rr];
      o.y = (short)t[c + 1][r + rr];
      o.z = (short)t[c + 2][r + rr];
      o.w = (short)t[c + 3][r + rr];
      *reinterpret_cast<short4*>(
          wT + (size_t)(bn * 64 + r + rr) * 1024 + bk * 64 + c) = o;
    }
  } else {
    const int b = bidx - 8960;
    int kept[4];
    int c = 0;
#pragma unroll
    for (int k = 0; k < 4; ++k) {
      const int j = tid * 4 + k;
      const int kp = (j == 0) ? 1 : (mask[b * (SEQ - 1) + j - 1] != 0);
      kept[k] = kp;
      c += kp;
    }
    sc[tid] = c;
    __syncthreads();
    for (int off = 1; off < 256; off <<= 1) {
      const int v = (tid >= off) ? sc[tid - off] : 0;
      __syncthreads();
      sc[tid] += v;
      __syncthreads();
    }
    int pos = sc[tid] - c;
    const int total = sc[255];
#pragma unroll
    for (int k = 0; k < 4; ++k) {
      const int j = tid * 4 + k;
      if (kept[k]) kl[b * SEQ + pos] = j;
      pos += kept[k];
    }
    if (tid == 0) nkeep[b] = total;
  }
}

// ---------------- Kernel 1: qkv GEMM, Q-full + KV-compacted -----------------
// ROUND-14/16 CONFIG — the measured local optimum (57.2-57.4us, VGPR 64,
// 18.4% occ). All 2-phase pipeline variants regressed against it:
//   r9 counted-vmcnt dbuf (67us), r10-12 256-tile (64us), r15 BK=32 (82us),
//   r17 single-barrier dbuf (69us) — each lost occupancy (LDS/VGPR) worth
//   more than the barrier-drain it saved. Do not change tile/BK/buffering.
// 128x128 tile, BK=64, single 32KB LDS buffer, XOR8 swizzle both sides.
// blocks [0,512):   Q  = x[all rows] @ wT[0:1024]      -> Qh (pre-scaled)
//   m FAST (bq&63): stride 64 ≡ 0 mod 8 -> each m-tile pinned to one XCD
//   across all n-passes (round-5/11 lesson: n-fast doubles FETCH).
// blocks [512,1536): KV = x[kept rows via kl] @ wT[1024:]
//   K -> Kc[bh][i][64] row-major; V -> Vt[bh][64 d][1024 i] TRANSPOSED
//   directly in the epilogue (d-major LDS bounce).
//   Pad/tail rows (i >= nk) hold finite garbage; annihilated by the
//   attention tail pen (exp2(s-14427)==0 in f32) — bit-exact.
__global__ __launch_bounds__(256, 4) void qkv_gemm(
    const unsigned short* __restrict__ x, const unsigned short* __restrict__ wT,
    const int* __restrict__ kl, const int* __restrict__ nkeep,
    unsigned short* __restrict__ Qh, unsigned short* __restrict__ Kc,
    unsigned short* __restrict__ Vt) {
  __shared__ alignas(16) unsigned char La[128 * 128];   // 16KB: A 128r x 64k
  __shared__ alignas(16) unsigned char Lb[128 * 128];   // 16KB: B 128r x 64k
  const int tid = threadIdx.x;
  const int lane = tid & 63;
  const int wave = tid >> 6;
  const int bq = blockIdx.x;

  int m0, n0, nkb;
  int srow[4];                       // global A-row per staged row slot
  const int rbase = tid >> 3;        // staged row offset within 32-row group
  if (bq < 512) {
    m0 = (bq & 63) * 128;            // m FAST: 64 M-tiles over 8192 rows
    n0 = (bq >> 6) * 128;            // 8 N-tiles over Q section (slow)
    nkb = 1 << 30;
#pragma unroll
    for (int r = 0; r < 4; ++r) srow[r] = m0 + r * 32 + rbase;
  } else {
    const int idx = bq - 512;
    const int nt = idx >> 6;         // 16 N-tiles (slow)
    const int bm = idx & 63;         // (b,mt) FAST
    const int b = bm >> 3;
    const int mt = bm & 7;           // 8 compact M-tiles of 128
    nkb = nkeep[b];
    const int m0c = mt * 128;
    if (m0c >= nkb) return;          // whole block exits before any barrier
    m0 = b * 1024 + m0c;             // epilogue: grow>>10 = b, grow&1023 = iv
    n0 = 1024 + nt * 128;
#pragma unroll
    for (int r = 0; r < 4; ++r) {
      int i = m0c + r * 32 + rbase;
      i = (i < nkb) ? i : (nkb - 1); // clamp pad rows to last kept row
      srow[r] = b * 1024 + kl[b * SEQ + i];
    }
  }

  const int wm = (wave >> 1) * 64;
  const int wn = (wave & 1) * 64;
  const int l15 = lane & 15;
  const int lg = lane >> 4;
  const int lg4 = lg * 4;
  const int scha = (tid & 7) ^ ((tid >> 3) & 7);   // thread-fixed src swizzle

  f32x4 acc[4][4] = {};

  auto STAGE = [&](int kt) {
#pragma unroll
    for (int r = 0; r < 4; ++r) {
      const int o = r * 4096 + tid * 16;
      gload_lds16(x + (size_t)srow[r] * DIM + kt + scha * 8, La + o);
      gload_lds16(wT + (size_t)(n0 + r * 32 + rbase) * DIM + kt + scha * 8,
                  Lb + o);
    }
  };

  for (int t = 0; t < 16; ++t) {
    const int kt = t * 64;
    __syncthreads();        // all waves done reading previous tile
    STAGE(kt);
    __syncthreads();        // tile resident (drains gload queue)
#pragma unroll
    for (int kk = 0; kk < 2; ++kk) {
      bf16x8 af[4], bfr[4];
#pragma unroll
      for (int i = 0; i < 4; ++i) {
        const int ra = wm + i * 16 + l15;
        af[i] = *reinterpret_cast<const bf16x8*>(
            La + ra * 128 + (((kk * 4 + lg) ^ (ra & 7)) << 4));
        const int rb = wn + i * 16 + l15;
        bfr[i] = *reinterpret_cast<const bf16x8*>(
            Lb + rb * 128 + (((kk * 4 + lg) ^ (rb & 7)) << 4));
      }
#pragma unroll
      for (int i = 0; i < 4; ++i)
#pragma unroll
        for (int j = 0; j < 4; ++j)
          acc[i][j] = __builtin_amdgcn_mfma_f32_16x16x32_bf16(
              af[i], bfr[j], acc[i][j], 0, 0, 0);
    }
  }

  // ---- epilogue: LDS bounce -> 16B coalesced stores ----
  __syncthreads();   // all waves done with La/Lb
  const int sec = n0 >> 10;              // block-uniform: 0=q 1=k 2=v
  const int h = ((n0 + wn) >> 6) & 15;   // wave-uniform head
  const int bb = m0 >> 10;
  if (sec < 2) {
    // row-major path (Q, K): Sw[16 rows][72]
    unsigned short* Sw = reinterpret_cast<unsigned short*>(La + wave * 2304);
    const float sc = (sec == 0) ? QSCALE_L2 : 1.0f;
#pragma unroll
    for (int i = 0; i < 4; ++i) {
#pragma unroll
      for (int j = 0; j < 4; ++j)
#pragma unroll
        for (int r = 0; r < 4; ++r)
          Sw[(lg4 + r) * 72 + j * 16 + l15] = f2bf(acc[i][j][r] * sc);
#pragma unroll
      for (int pass = 0; pass < 2; ++pass) {
        const int row = pass * 8 + (lane >> 3);
        const int chunk = lane & 7;
        const bf16x8 vv = *reinterpret_cast<const bf16x8*>(&Sw[row * 72 + chunk * 8]);
        const int grow = m0 + wm + i * 16 + row;
        const int b = grow >> 10;
        const int n = grow & 1023;
        const size_t bh = (size_t)b * HEADS + h;
        if (sec == 0) {
          *reinterpret_cast<bf16x8*>(&Qh[(bh * SEQ + n) * DH + chunk * 8]) = vv;
        } else if (n < nkb) {            // n IS the compact index here
          *reinterpret_cast<bf16x8*>(&Kc[(bh * SEQ + n) * DH + chunk * 8]) = vv;
        }
      }
    }
  } else {
    // V path: d-major bounce Sv[64 d][24-short stride] -> direct transposed
    // store Vt[bh][d][iv]. Lane owns d=lane, stores two contiguous 16B
    // chunks (i 0-7, 8-15) -> lane's 32B contiguous; 64B lines complete
    // across the wave's four i-subtiles (merge in L2).
    unsigned short* Sv = reinterpret_cast<unsigned short*>(La + wave * 3072);
    const size_t bh = (size_t)bb * HEADS + h;
    unsigned short* vbase = Vt + (bh * DH + lane) * SEQ;
#pragma unroll
    for (int i = 0; i < 4; ++i) {
#pragma unroll
      for (int j = 0; j < 4; ++j)
#pragma unroll
        for (int r = 0; r < 4; ++r)
          Sv[(j * 16 + l15) * 24 + lg4 + r] = f2bf(acc[i][j][r]);
      const int iv0 = (m0 & 1023) + wm + i * 16;   // compact-i base, mult of 16
      const bf16x8 v0 = *reinterpret_cast<const bf16x8*>(&Sv[lane * 24 + 0]);
      const bf16x8 v1 = *reinterpret_cast<const bf16x8*>(&Sv[lane * 24 + 8]);
      *reinterpret_cast<bf16x8*>(vbase + iv0 + 0) = v0;
      *reinterpret_cast<bf16x8*>(vbase + iv0 + 8) = v1;
    }
  }
}

// ---------------- Kernel 2: flash attention over compacted KV ---------------
// block = 4 waves x 32 q-rows of one (b,h); 32x32x16 MFMA.
// K and V staged in double-buffered LDS via global_load_lds (one copy/block).
// XOR chunk-swizzle on the GLOBAL source + ds_read address (rule #21).
// Mask pen is tail-tile-only and computed in registers (kv < nk).
__global__ __launch_bounds__(256) void attn_fwd5(
    const unsigned short* __restrict__ Qh, const unsigned short* __restrict__ Kc,
    const unsigned short* __restrict__ Vtc,
    const int* __restrict__ nkeep, float* __restrict__ out) {
  __shared__ alignas(16) unsigned char Kl[2][8192];
  __shared__ alignas(16) unsigned char Vl[2][8192];
  __shared__ float corrw[4][32];
  const int tid = threadIdx.x;
  const int lane = tid & 63;
  const int wave = tid >> 6;
  const int l31 = lane & 31;
  const int hi = lane >> 5;
  const int h8 = hi * 8;
  const bool islo = lane < 32;

  // XCD swizzle: 128 consecutive logical blocks (16 heads) per XCD
  const int bid = ((blockIdx.x & 7) << 7) | (blockIdx.x >> 3);
  const int b = bid >> 7;
  const int hh = (bid >> 3) & 15;
  const int qc = bid & 7;
  const size_t bh = (size_t)b * HEADS + hh;
  const int q0 = qc * 128 + wave * 32;

  const int nk = nkeep[b];
  const int ntile = (nk + 63) >> 6;

  const unsigned short* Q = Qh + bh * SEQ * DH;
  const unsigned short* K = Kc + bh * SEQ * DH;
  const unsigned short* V = Vtc + bh * DH * SEQ;   // [64][1024] compacted cols

  auto STAGE = [&](int buf, int kt) {
#pragma unroll
    for (int p = 0; p < 2; ++p) {
      const int off = p * 4096 + tid * 16;
      const int row = off >> 7;
      const int chunk = (off >> 4) & 7;
      const int sch = chunk ^ (row & 7);
      gload_lds16(K + (size_t)(kt + row) * DH + sch * 8, &Kl[buf][off]);
      gload_lds16(V + (size_t)row * SEQ + kt + sch * 8, &Vl[buf][off]);
    }
  };

  STAGE(0, 0);

  bf16x8 qf[4];
#pragma unroll
  for (int ds = 0; ds < 4; ++ds)
    qf[ds] = *reinterpret_cast<const bf16x8*>(
        Q + (size_t)(q0 + l31) * DH + ds * 16 + h8);

  u32x4 onesu = {0u, 0u, 0u, 0u};
  onesu.x = islo ? 0x3F80u : 0u;     // bf16 1.0 at k==0 of lane-half 0
  const bf16x8 onesf = __builtin_bit_cast(bf16x8, onesu);

  f32x16 Od0 = (f32x16)0.f, Od1 = (f32x16)0.f;
  float m_ = 0.f, l_ = 0.f;

  __syncthreads();   // drains prologue STAGE

  int cur = 0;
  for (int ti = 0; ti < ntile; ++ti) {
    const int kt = ti * 64;
    if (ti + 1 < ntile) STAGE(cur ^ 1, kt + 64);

    // ---- S^T = K·Q^T from LDS (swizzled ds_read_b128) ----
    f32x16 st0 = (f32x16)0.f, st1 = (f32x16)0.f;
    __builtin_amdgcn_s_setprio(1);
#pragma unroll
    for (int ds = 0; ds < 4; ++ds) {
      const int c0 = (ds * 2 + hi) ^ (l31 & 7);
      const bf16x8 kf0 = *reinterpret_cast<const bf16x8*>(
          &Kl[cur][l31 * 128 + c0 * 16]);
      st0 = __builtin_amdgcn_mfma_f32_32x32x16_bf16(kf0, qf[ds], st0, 0, 0, 0);
      const bf16x8 kf1 = *reinterpret_cast<const bf16x8*>(
          &Kl[cur][(32 + l31) * 128 + c0 * 16]);
      st1 = __builtin_amdgcn_mfma_f32_32x32x16_bf16(kf1, qf[ds], st1, 0, 0, 0);
    }
    __builtin_amdgcn_s_setprio(0);

    // tail-only mask via rank-1 MFMA: st[kv][q] += pen[kv], pen = (kv<nk)?0:-1e4*log2e
    if (ti == ntile - 1) {
      const unsigned short pv = f2bf(PEN_L2);
      const unsigned short pu0 = (kt + l31 < nk) ? (unsigned short)0 : pv;
      const unsigned short pu1 = (kt + 32 + l31 < nk) ? (unsigned short)0 : pv;
      u32x4 p0 = {0u, 0u, 0u, 0u}, p1 = {0u, 0u, 0u, 0u};
      p0.x = islo ? (unsigned)pu0 : 0u;
      p1.x = islo ? (unsigned)pu1 : 0u;
      st0 = __builtin_amdgcn_mfma_f32_32x32x16_bf16(
          __builtin_bit_cast(bf16x8, p0), onesf, st0, 0, 0, 0);
      st1 = __builtin_amdgcn_mfma_f32_32x32x16_bf16(
          __builtin_bit_cast(bf16x8, p1), onesf, st1, 0, 0, 0);
    }
    // row max
    float a[8];
#pragma unroll
    for (int i = 0; i < 8; ++i)
      a[i] = fmaxf(fmaxf(st0[i], st0[i + 8]), fmaxf(st1[i], st1[i + 8]));
#pragma unroll
    for (int k = 4; k >= 1; k >>= 1)
#pragma unroll
      for (int i = 0; i < k; ++i) a[i] = fmaxf(a[i], a[i + k]);
    const float mx = fmaxf(a[0], __shfl_xor(a[0], 32));
    // deferred rescale (rare)
    if (!__all(mx <= m_ + THR_L2)) {
      const float mn = fmaxf(m_, mx);
      const float corr = fexp2(m_ - mn);
      m_ = mn;
      l_ *= corr;
      if (islo) corrw[wave][l31] = corr;
      f32x4 cv[4];
#pragma unroll
      for (int j = 0; j < 4; ++j)
        cv[j] = *reinterpret_cast<const f32x4*>(&corrw[wave][j * 8 + (h8 >> 1)]);
#pragma unroll
      for (int r = 0; r < 16; ++r) {
        Od0[r] *= cv[r >> 2][r & 3];
        Od1[r] *= cv[r >> 2][r & 3];
      }
    }
    // P = exp2(st - m)
#pragma unroll
    for (int i = 0; i < 16; ++i) {
      st0[i] = fexp2(st0[i] - m_);
      st1[i] = fexp2(st1[i] - m_);
    }
    // row sum
    float s8[8];
#pragma unroll
    for (int i = 0; i < 8; ++i)
      s8[i] = (st0[i] + st0[i + 8]) + (st1[i] + st1[i + 8]);
#pragma unroll
    for (int k = 4; k >= 1; k >>= 1)
#pragma unroll
      for (int i = 0; i < k; ++i) s8[i] += s8[i + k];
    l_ += s8[0] + __shfl_xor(s8[0], 32);
    // pack P -> A-frags (cvt_pk + permlane32_swap)
    bf16x8 pf[4];
#pragma unroll
    for (int t = 0; t < 2; ++t) {
#pragma unroll
      for (int bq = 0; bq < 2; ++bq) {
        const int o = 8 * bq;
        float e0 = t ? st1[o + 0] : st0[o + 0], e1 = t ? st1[o + 1] : st0[o + 1];
        float e2 = t ? st1[o + 2] : st0[o + 2], e3 = t ? st1[o + 3] : st0[o + 3];
        float e4 = t ? st1[o + 4] : st0[o + 4], e5 = t ? st1[o + 5] : st0[o + 5];
        float e6 = t ? st1[o + 6] : st0[o + 6], e7 = t ? st1[o + 7] : st0[o + 7];
        unsigned A0, A1, B0, B1;
        asm("v_cvt_pk_bf16_f32 %0, %1, %2" : "=v"(A0) : "v"(e0), "v"(e1));
        asm("v_cvt_pk_bf16_f32 %0, %1, %2" : "=v"(A1) : "v"(e2), "v"(e3));
        asm("v_cvt_pk_bf16_f32 %0, %1, %2" : "=v"(B0) : "v"(e4), "v"(e5));
        asm("v_cvt_pk_bf16_f32 %0, %1, %2" : "=v"(B1) : "v"(e6), "v"(e7));
        asm("v_permlane32_swap_b32 %0, %1\n\ts_nop 1" : "+v"(A0), "+v"(B0));
        asm("v_permlane32_swap_b32 %0, %1\n\ts_nop 1" : "+v"(A1), "+v"(B1));
        u32x4 pk4;
        pk4.x = A0; pk4.y = A1; pk4.z = B0; pk4.w = B1;
        pf[t * 2 + bq] = __builtin_bit_cast(bf16x8, pk4);
      }
    }
    // ---- PV from LDS V tile (swizzled ds_read_b128) ----
    __builtin_amdgcn_s_setprio(1);
#pragma unroll
    for (int kvs = 0; kvs < 4; ++kvs) {
      const int c0 = (kvs * 2 + hi) ^ (l31 & 7);
      const bf16x8 v0 = *reinterpret_cast<const bf16x8*>(
          &Vl[cur][l31 * 128 + c0 * 16]);
      Od0 = __builtin_amdgcn_mfma_f32_32x32x16_bf16(pf[kvs], v0, Od0, 0, 0, 0);
      const bf16x8 v1 = *reinterpret_cast<const bf16x8*>(
          &Vl[cur][(32 + l31) * 128 + c0 * 16]);
      Od1 = __builtin_amdgcn_mfma_f32_32x32x16_bf16(pf[kvs], v1, Od1, 0, 0, 0);
    }
    __builtin_amdgcn_s_setprio(0);

    __syncthreads();
    cur ^= 1;
  }

  // epilogue: O / l
  if (islo) corrw[wave][l31] = 1.0f / l_;
  f32x4 lv[4];
#pragma unroll
  for (int j = 0; j < 4; ++j)
    lv[j] = *reinterpret_cast<const f32x4*>(&corrw[wave][j * 8 + (h8 >> 1)]);
#pragma unroll
  for (int r = 0; r < 16; ++r) {
    const int q = q0 + (r & 3) + 8 * (r >> 2) + (hi << 2);
    out[((size_t)b * SEQ + q) * (HEADS * DH) + hh * DH + 0 * 32 + l31] =
        Od0[r] * lv[r >> 2][r & 3];
    out[((size_t)b * SEQ + q) * (HEADS * DH) + hh * DH + 1 * 32 + l31] =
        Od1[r] * lv[r >> 2][r & 3];
  }
}

// ---------------- launch ----------------------------------------------------
extern "C" void kernel_launch(void* const* d_in, const int* in_sizes, int n_in,
                              void* d_out, int out_size, void* d_ws, size_t ws_size,
                              hipStream_t stream) {
  const float* x = (const float*)d_in[0];
  const int* mask = (const int*)d_in[1];
  const float* w = (const float*)d_in[2];
  float* outp = (float*)d_out;

  char* ws = (char*)d_ws;
  unsigned short* xb   = (unsigned short*)(ws);                  // 16777216 B
  unsigned short* wT   = (unsigned short*)(ws + 16777216);       //  6291456 B
  unsigned short* Qh   = (unsigned short*)(ws + 23068672);       // 16777216 B
  unsigned short* Kc   = (unsigned short*)(ws + 39845888);       // 16777216 B
  unsigned short* Vt   = (unsigned short*)(ws + 56623104);       // 16777216 B
  int*            kl   = (int*)(ws + 73400320);                  //    32768 B
  int*            nkp  = (int*)(ws + 73433088);                  //       32 B

  prep<<<dim3(8968), 256, 0, stream>>>(x, xb, w, wT, mask, kl, nkp);
  qkv_gemm<<<dim3(1536), 256, 0, stream>>>(xb, wT, kl, nkp, Qh, Kc, Vt);
  attn_fwd5<<<dim3(1024), 256, 0, stream>>>(Qh, Kc, Vt, nkp, outp);
}